// Round 7
// baseline (228.518 us; speedup 1.0000x reference)
//
#include <hip/hip_runtime.h>
#include <hip/hip_bf16.h>

#define B_   2
#define N_   2048
#define DIM_ 1024
#define HD_  64
#define DV_  128

typedef __bf16 bf16;
typedef __bf16 bf16x8 __attribute__((ext_vector_type(8)));
typedef __bf16 bf16x4 __attribute__((ext_vector_type(4)));
typedef float  floatx4 __attribute__((ext_vector_type(4)));

#if __has_builtin(__builtin_amdgcn_exp2f)
#define EXP2(x) __builtin_amdgcn_exp2f(x)
#else
#define EXP2(x) exp2f(x)
#endif

// Q scale: hd^-0.5 (=1/8) with log2(e) folded in so softmax uses raw v_exp_f32 (2^x).
#define QSCALE 0.1803368801111244f

__device__ __forceinline__ void async16(const void* g, void* l) {
  __builtin_amdgcn_global_load_lds(
      (__attribute__((address_space(1))) void*)g,
      (__attribute__((address_space(3))) void*)l, 16, 0, 0);
}

// ---------------- convert fp32 -> bf16 (x + 4 weights, contiguous dst) ----------------
__global__ void convert_kernel(const float* __restrict__ x,
                               const float* __restrict__ wq,
                               const float* __restrict__ wk,
                               const float* __restrict__ wv,
                               const float* __restrict__ wo,
                               bf16* __restrict__ dst) {
  const int NX = B_ * N_ * DIM_;   // 4194304
  const int NW = DIM_ * DIM_;      // 1048576 = 2^20
  int i = (blockIdx.x * 256 + threadIdx.x) * 4;
  const float* src;
  int off;
  if (i < NX) { src = x; off = i; }
  else {
    int j = i - NX;
    int w = j >> 20;
    off = j & (NW - 1);
    src = (w == 0) ? wq : (w == 1) ? wk : (w == 2) ? wv : wo;
  }
  float4 v = *(const float4*)(src + off);
  bf16x4 o = { (bf16)v.x, (bf16)v.y, (bf16)v.z, (bf16)v.w };
  *(bf16x4*)(dst + i) = o;
}

// ---------------- lambda scalar ----------------
__global__ void lam_kernel(const float* __restrict__ lq1, const float* __restrict__ lk1,
                           const float* __restrict__ lq2, const float* __restrict__ lk2,
                           float* __restrict__ lam_out) {
  int l = threadIdx.x;  // 64 threads
  float a = lq1[l] * lk1[l];
  float b = lq2[l] * lk2[l];
  for (int m = 1; m < 64; m <<= 1) {
    a += __shfl_xor(a, m, 64);
    b += __shfl_xor(b, m, 64);
  }
  if (l == 0) *lam_out = __expf(a) - __expf(b) + 0.8f;
}

// ---------------- QKV projection GEMM (z=0:Q, 1:K, 2:V-transposed) ----------------
// 512 threads = 8 waves (wave tile 32x64) for 2x latency hiding vs 4-wave blocks:
// 3 blocks/CU co-resident -> up to 24 waves/CU on the barrier-drain loop.
__global__ __launch_bounds__(512) void proj_kernel(
    const bf16* __restrict__ xb, const bf16* __restrict__ wall,
    const float* __restrict__ bq, const float* __restrict__ bk,
    const float* __restrict__ bv,
    bf16* __restrict__ qo, bf16* __restrict__ ko, bf16* __restrict__ vt) {
  __shared__ __align__(16) bf16 SM[2 * 128 * 64];  // At | Bt; reused as V^T tile
  bf16* At = SM;
  bf16* Bt = SM + 128 * 64;
  const int tid = threadIdx.x, lane = tid & 63, w = tid >> 6;
  const int tm = blockIdx.x, tn = blockIdx.y, z = blockIdx.z;
  const int quad = lane >> 4, l15 = lane & 15;
  const int wm = (w & 3) * 32, wn = (w >> 2) * 64;
  const bf16* Ab = xb + (long)tm * 128 * DIM_;
  const bf16* Bb = wall + (long)z * (DIM_ * DIM_) + (long)tn * 128 * DIM_;
  floatx4 zero = {0.f, 0.f, 0.f, 0.f};
  floatx4 acc[2][4];
#pragma unroll
  for (int i = 0; i < 2; ++i)
#pragma unroll
    for (int j = 0; j < 4; ++j) acc[i][j] = zero;

  for (int kb = 0; kb < DIM_ / 64; ++kb) {
    for (int idx = tid; idx < 1024; idx += 512) {
      int row = idx >> 3, ch = idx & 7, g = ch ^ (row & 7);
      async16(Ab + row * DIM_ + kb * 64 + g * 8, (char*)At + (idx - lane) * 16);
      async16(Bb + row * DIM_ + kb * 64 + g * 8, (char*)Bt + (idx - lane) * 16);
    }
    __syncthreads();
#pragma unroll
    for (int ks = 0; ks < 2; ++ks) {
      bf16x8 af[2], bfm[4];
#pragma unroll
      for (int mt = 0; mt < 2; ++mt) {
        int r = wm + mt * 16 + l15;
        af[mt] = *(const bf16x8*)&At[r * 64 + ((ks * 4 + quad) ^ (r & 7)) * 8];
      }
#pragma unroll
      for (int nt = 0; nt < 4; ++nt) {
        int r = wn + nt * 16 + l15;
        bfm[nt] = *(const bf16x8*)&Bt[r * 64 + ((ks * 4 + quad) ^ (r & 7)) * 8];
      }
#pragma unroll
      for (int mt = 0; mt < 2; ++mt)
#pragma unroll
        for (int nt = 0; nt < 4; ++nt)
          acc[mt][nt] = __builtin_amdgcn_mfma_f32_16x16x32_bf16(
              af[mt], bfm[nt], acc[mt][nt], 0, 0, 0);
    }
    __syncthreads();
  }

  if (z != 2) {
    // Q / K epilogue: D row=(quad*4+r), col=l15 per 16x16 tile
#pragma unroll
    for (int mt = 0; mt < 2; ++mt)
#pragma unroll
      for (int nt = 0; nt < 4; ++nt)
#pragma unroll
        for (int r = 0; r < 4; ++r) {
          int grow = tm * 128 + wm + mt * 16 + quad * 4 + r;
          int gcol = tn * 128 + wn + nt * 16 + l15;
          float v = acc[mt][nt][r];
          if (z == 0) {
            qo[(long)grow * DIM_ + gcol] = (bf16)((v + bq[gcol]) * QSCALE);
          } else {
            ko[(long)grow * DIM_ + gcol] = (bf16)(v + bk[gcol]);
          }
        }
  } else {
    // V epilogue: transpose through LDS (b64 swizzled writes, b128 reads),
    // then coalesced 256B-contiguous V^T row stores. e == tn (128-aligned).
    bf16* Vl = SM;  // [d 128][key-chunk swizzled] 32 KB, overlays At/Bt (loop done)
#pragma unroll
    for (int nt = 0; nt < 4; ++nt) {
      int d = wn + nt * 16 + l15;
      float bvv = bv[tn * 128 + d];
      int m = (d & 7) * 2;
#pragma unroll
      for (int mt = 0; mt < 2; ++mt) {
        bf16x4 v4 = { (bf16)(acc[mt][nt][0] + bvv), (bf16)(acc[mt][nt][1] + bvv),
                      (bf16)(acc[mt][nt][2] + bvv), (bf16)(acc[mt][nt][3] + bvv) };
        int c = (wm >> 2) + mt * 4 + quad;       // key chunk (4 keys), [0,32)
        *(bf16x4*)&Vl[d * 128 + (c ^ m) * 4] = v4;
      }
    }
    __syncthreads();
    const int bb = tm >> 4, e = tn;
    const long rowbase = ((long)(bb * 8 + e) * 128) * (long)N_ + (tm & 15) * 128;
#pragma unroll
    for (int p = 0; p < 4; ++p) {
      int d = p * 32 + (tid >> 4), j = tid & 15;
      int cs = (2 * j) ^ ((d & 7) * 2);
      bf16x8 val = *(const bf16x8*)&Vl[d * 128 + cs * 4];
      *(bf16x8*)&vt[rowbase + (long)d * N_ + j * 8] = val;
    }
  }
}

// ---------------- fused pair flash attention + diff + RMSNorm ----------------
// One block = one (b, e, 64-query tile). 256 threads = 4 waves; wave w owns
// query rows w*16..+15, computing BOTH heads of the diff pair. K/V double-
// buffered, ONE barrier per k-tile (prefetch issued post-barrier overlaps
// compute). S is computed TRANSPOSED (mfma(K_frag, Q_frag) -> S^T: lane holds
// q=l15, keys quad*4+r per nt-tile) so P goes to LDS as [q][key] with b64
// writes and is read back as contiguous b64 pairs for the PV A-fragment --
// 8 b64 writes vs 64 scalar b16. Row-sum is one scalar per lane. Epilogue
// (diff + headwise RMSNorm + 0.2, bf16) in-register per wave.
__global__ __launch_bounds__(256, 2) void attn_kernel(
    const bf16* __restrict__ qb, const bf16* __restrict__ kbuf,
    const bf16* __restrict__ vt, const float* __restrict__ lamp,
    const float* __restrict__ norm_w, bf16* __restrict__ ao) {
  __shared__ __align__(16) bf16 Kt[2][2 * 64 * 64];  // [buf][head][key][hd] 32 KB
  __shared__ __align__(16) bf16 Vt[2][128 * 64];     // [buf][d][key]        32 KB
  __shared__ __align__(16) bf16 Pt[4][2][16 * 64];   // [wave][head][q][key] 16 KB

  const int tid = threadIdx.x, lane = tid & 63, w = tid >> 6;
  const int qt = blockIdx.x, e = blockIdx.y, b = blockIdx.z;
  const int quad = lane >> 4, l15 = lane & 15;
  floatx4 zero = {0.f, 0.f, 0.f, 0.f};

  // Q fragments (B-operand: B[n=q=l15][k=quad*8+j]), both heads, loop-invariant.
  const int qrow = qt * 64 + w * 16 + l15;
  const bf16* qrp = qb + (long)(b * N_ + qrow) * DIM_ + e * 128;
  bf16x8 qf0[2], qf1[2];
  qf0[0] = *(const bf16x8*)(qrp + quad * 8);
  qf0[1] = *(const bf16x8*)(qrp + 32 + quad * 8);
  qf1[0] = *(const bf16x8*)(qrp + 64 + quad * 8);
  qf1[1] = *(const bf16x8*)(qrp + 96 + quad * 8);

  const bf16* kbase = kbuf + (long)b * N_ * DIM_ + e * 128;
  const bf16* vbase = vt + (long)(b * 8 + e) * DV_ * N_;

  floatx4 acc0[8], acc1[8];
#pragma unroll
  for (int i = 0; i < 8; ++i) { acc0[i] = zero; acc1[i] = zero; }
  float lp0 = 0.f, lp1 = 0.f;  // per-lane row-sum partial (q = l15 fixed per lane)

  bf16* Pt0 = Pt[w][0];
  bf16* Pt1 = Pt[w][1];

#define STAGE(ktv, bufv)                                                            \
  {                                                                                 \
    int kt_ = (ktv), buf_ = (bufv);                                                 \
    _Pragma("unroll") for (int t = 0; t < 4; ++t) {                                 \
      int idx = tid + t * 256;                                                      \
      int khl = idx >> 9, row = (idx >> 3) & 63, ch = idx & 7, g = ch ^ (row & 7);  \
      async16(kbase + ((long)(kt_ * 64 + row)) * DIM_ + khl * 64 + g * 8,           \
              (char*)Kt[buf_] + (idx - lane) * 16);                                 \
    }                                                                               \
    _Pragma("unroll") for (int t = 0; t < 4; ++t) {                                 \
      int idx = tid + t * 256;                                                      \
      int row = idx >> 3, ch = idx & 7, g = ch ^ (row & 7);                         \
      async16(vbase + (long)row * N_ + kt_ * 64 + g * 8,                            \
              (char*)Vt[buf_] + (idx - lane) * 16);                                 \
    }                                                                               \
  }

  STAGE(0, 0);

  for (int kt = 0; kt < N_ / 64; ++kt) {
    const int buf = kt & 1;
    __syncthreads();                 // drains prefetch of buf (issued last iter)
    if (kt + 1 < N_ / 64) STAGE(kt + 1, buf ^ 1);  // overlaps with compute below

    const bf16* Kh0 = Kt[buf];
    const bf16* Kh1 = Kt[buf] + 4096;
    const bf16* Vb = Vt[buf];

    // S^T = mfma(A=K_frag, B=Q_frag): D[m=key][n=q]; lane: q=l15, key=nt*16+quad*4+r
    floatx4 s0[4], s1[4];
#pragma unroll
    for (int nt = 0; nt < 4; ++nt) { s0[nt] = zero; s1[nt] = zero; }
#pragma unroll
    for (int ks = 0; ks < 2; ++ks) {
#pragma unroll
      for (int nt = 0; nt < 4; ++nt) {
        int br = nt * 16 + l15;
        int so = ((ks * 4 + quad) ^ (br & 7)) * 8;
        bf16x8 k0 = *(const bf16x8*)&Kh0[br * 64 + so];
        bf16x8 k1 = *(const bf16x8*)&Kh1[br * 64 + so];
        s0[nt] = __builtin_amdgcn_mfma_f32_16x16x32_bf16(k0, qf0[ks], s0[nt], 0, 0, 0);
        s1[nt] = __builtin_amdgcn_mfma_f32_16x16x32_bf16(k1, qf1[ks], s1[nt], 0, 0, 0);
      }
    }

    // p = 2^s; P^T -> P[q][key] in LDS via b64 chunk writes (chunk c = nt*4+quad,
    // XOR-swizzled by l15); per-lane scalar row-sum (q fixed = l15).
#pragma unroll
    for (int nt = 0; nt < 4; ++nt) {
      float p0 = EXP2(s0[nt][0]), p1 = EXP2(s0[nt][1]);
      float p2 = EXP2(s0[nt][2]), p3 = EXP2(s0[nt][3]);
      lp0 += (p0 + p1) + (p2 + p3);
      bf16x4 v0 = { (bf16)p0, (bf16)p1, (bf16)p2, (bf16)p3 };
      int c = nt * 4 + quad;
      *(bf16x4*)&Pt0[l15 * 64 + (c ^ l15) * 4] = v0;
      float u0 = EXP2(s1[nt][0]), u1 = EXP2(s1[nt][1]);
      float u2 = EXP2(s1[nt][2]), u3 = EXP2(s1[nt][3]);
      lp1 += (u0 + u1) + (u2 + u3);
      bf16x4 v1 = { (bf16)u0, (bf16)u1, (bf16)u2, (bf16)u3 };
      *(bf16x4*)&Pt1[l15 * 64 + (c ^ l15) * 4] = v1;
    }

    // O += P @ V : A = P[q=l15][key=32ks+quad*8+j] (two swizzled b64 chunks),
    // B = V^T[d][key] (Vt). Same-wave RAW on Pt, no barrier.
#pragma unroll
    for (int ks = 0; ks < 2; ++ks) {
      int c0 = 8 * ks + 2 * quad;
      bf16x4 a0lo = *(const bf16x4*)&Pt0[l15 * 64 + ((c0) ^ l15) * 4];
      bf16x4 a0hi = *(const bf16x4*)&Pt0[l15 * 64 + ((c0 + 1) ^ l15) * 4];
      bf16x4 a1lo = *(const bf16x4*)&Pt1[l15 * 64 + ((c0) ^ l15) * 4];
      bf16x4 a1hi = *(const bf16x4*)&Pt1[l15 * 64 + ((c0 + 1) ^ l15) * 4];
      bf16x8 af0 = __builtin_shufflevector(a0lo, a0hi, 0, 1, 2, 3, 4, 5, 6, 7);
      bf16x8 af1 = __builtin_shufflevector(a1lo, a1hi, 0, 1, 2, 3, 4, 5, 6, 7);
#pragma unroll
      for (int dt = 0; dt < 8; ++dt) {
        int br = dt * 16 + l15;
        bf16x8 bfm = *(const bf16x8*)&Vb[br * 64 + ((ks * 4 + quad) ^ (br & 7)) * 8];
        acc0[dt] = __builtin_amdgcn_mfma_f32_16x16x32_bf16(af0, bfm, acc0[dt], 0, 0, 0);
        acc1[dt] = __builtin_amdgcn_mfma_f32_16x16x32_bf16(af1, bfm, acc1[dt], 0, 0, 0);
      }
    }
  }

  // row sums: reduce across quads (lanes sharing l15), then redistribute to
  // the acc layout's q = quad*4+r via lane shuffle.
  lp0 += __shfl_xor(lp0, 16, 64);
  lp0 += __shfl_xor(lp0, 32, 64);
  lp1 += __shfl_xor(lp1, 16, 64);
  lp1 += __shfl_xor(lp1, 32, 64);
  float inv0[4], inv1[4];
#pragma unroll
  for (int r = 0; r < 4; ++r) {
    inv0[r] = 1.0f / __shfl(lp0, quad * 4 + r, 64);
    inv1[r] = 1.0f / __shfl(lp1, quad * 4 + r, 64);
  }

  // in-register epilogue: diff + headwise RMSNorm + 0.2 scale, bf16 store
  float lam = *lamp;
  float ss[4] = {0.f, 0.f, 0.f, 0.f};
#pragma unroll
  for (int dt = 0; dt < 8; ++dt)
#pragma unroll
    for (int r = 0; r < 4; ++r) {
      float v = acc0[dt][r] * inv0[r] - lam * (acc1[dt][r] * inv1[r]);
      acc0[dt][r] = v;
      ss[r] += v * v;
    }
  float rms[4];
#pragma unroll
  for (int r = 0; r < 4; ++r) {
    float t = ss[r];
#pragma unroll
    for (int msk = 1; msk < 16; msk <<= 1) t += __shfl_xor(t, msk, 16);
    rms[r] = rsqrtf(t * (1.0f / 128.0f) + 1e-5f);
  }
#pragma unroll
  for (int dt = 0; dt < 8; ++dt) {
    float nwv = norm_w[dt * 16 + l15] * 0.2f;
#pragma unroll
    for (int r = 0; r < 4; ++r) {
      int n = qt * 64 + w * 16 + quad * 4 + r;
      ao[((long)(b * N_ + n)) * DIM_ + e * DV_ + dt * 16 + l15] =
          (bf16)(acc0[dt][r] * rms[r] * nwv);
    }
  }
}

// ---------------- output projection GEMM -> fp32 ----------------
// 64x128 tiles, grid (64,8) = 512 blocks = 2 blocks/CU (8 waves/CU) --
// the previous 128x128 grid was 256 blocks = 1 block/CU = 1 wave/SIMD.
__global__ __launch_bounds__(256) void out_gemm(
    const bf16* __restrict__ ab, const bf16* __restrict__ wo,
    const float* __restrict__ bo, float* __restrict__ out) {
  __shared__ __align__(16) bf16 At[64 * 64];
  __shared__ __align__(16) bf16 Bt[128 * 64];
  const int tid = threadIdx.x, lane = tid & 63, w = tid >> 6;
  const int tm = blockIdx.x, tn = blockIdx.y;
  const int quad = lane >> 4, l15 = lane & 15;
  const int wm = (w & 1) * 32, wn = (w >> 1) * 64;
  const bf16* Ab = ab + (long)tm * 64 * DIM_;
  const bf16* Bb = wo + (long)tn * 128 * DIM_;
  floatx4 zero = {0.f, 0.f, 0.f, 0.f};
  floatx4 acc[2][4];
#pragma unroll
  for (int i = 0; i < 2; ++i)
#pragma unroll
    for (int j = 0; j < 4; ++j) acc[i][j] = zero;

  for (int kb = 0; kb < DIM_ / 64; ++kb) {
    for (int idx = tid; idx < 512; idx += 256) {
      int row = idx >> 3, ch = idx & 7, g = ch ^ (row & 7);
      async16(Ab + row * DIM_ + kb * 64 + g * 8, (char*)At + (idx - lane) * 16);
    }
    for (int idx = tid; idx < 1024; idx += 256) {
      int row = idx >> 3, ch = idx & 7, g = ch ^ (row & 7);
      async16(Bb + row * DIM_ + kb * 64 + g * 8, (char*)Bt + (idx - lane) * 16);
    }
    __syncthreads();
#pragma unroll
    for (int ks = 0; ks < 2; ++ks) {
      bf16x8 af[2], bfm[4];
#pragma unroll
      for (int mt = 0; mt < 2; ++mt) {
        int r = wm + mt * 16 + l15;
        af[mt] = *(const bf16x8*)&At[r * 64 + ((ks * 4 + quad) ^ (r & 7)) * 8];
      }
#pragma unroll
      for (int nt = 0; nt < 4; ++nt) {
        int r = wn + nt * 16 + l15;
        bfm[nt] = *(const bf16x8*)&Bt[r * 64 + ((ks * 4 + quad) ^ (r & 7)) * 8];
      }
#pragma unroll
      for (int mt = 0; mt < 2; ++mt)
#pragma unroll
        for (int nt = 0; nt < 4; ++nt)
          acc[mt][nt] = __builtin_amdgcn_mfma_f32_16x16x32_bf16(
              af[mt], bfm[nt], acc[mt][nt], 0, 0, 0);
    }
    __syncthreads();
  }
#pragma unroll
  for (int mt = 0; mt < 2; ++mt)
#pragma unroll
    for (int nt = 0; nt < 4; ++nt)
#pragma unroll
      for (int r = 0; r < 4; ++r) {
        int grow = tm * 64 + wm + mt * 16 + quad * 4 + r;
        int gcol = tn * 128 + wn + nt * 16 + l15;
        out[(long)grow * DIM_ + gcol] = acc[mt][nt][r] + bo[gcol];
      }
}

extern "C" void kernel_launch(void* const* d_in, const int* in_sizes, int n_in,
                              void* d_out, int out_size, void* d_ws, size_t ws_size,
                              hipStream_t stream) {
  const float* x    = (const float*)d_in[0];
  const float* Wq   = (const float*)d_in[1];
  const float* bq   = (const float*)d_in[2];
  const float* Wk   = (const float*)d_in[3];
  const float* bk   = (const float*)d_in[4];
  const float* Wv   = (const float*)d_in[5];
  const float* bv   = (const float*)d_in[6];
  const float* Wo   = (const float*)d_in[7];
  const float* bo   = (const float*)d_in[8];
  const float* nw   = (const float*)d_in[9];
  const float* lq1  = (const float*)d_in[10];
  const float* lk1  = (const float*)d_in[11];
  const float* lq2  = (const float*)d_in[12];
  const float* lk2  = (const float*)d_in[13];

  char* ws = (char*)d_ws;
  float* lam = (float*)ws;                     // 256 B
  bf16* xb   = (bf16*)(ws + 256);              // [4096,1024] bf16
  bf16* wqb  = xb + 4194304;                   // Wq,Wk,Wv,Wo bf16 contiguous
  bf16* qb   = wqb + 4 * 1048576;              // Q scaled  [4096,1024]
  bf16* kbuf = qb + 4194304;                   // K         [4096,1024]
  bf16* vtb  = kbuf + 4194304;                 // V^T [b,e,d,key] = [16,128,2048]
  bf16* ab   = vtb + 4194304;                  // attn out  [4096,1024]

  convert_kernel<<<8192, 256, 0, stream>>>(x, Wq, Wk, Wv, Wo, xb);
  lam_kernel<<<1, 64, 0, stream>>>(lq1, lk1, lq2, lk2, lam);
  proj_kernel<<<dim3(32, 8, 3), 512, 0, stream>>>(xb, wqb, bq, bk, bv, qb, kbuf, vtb);
  attn_kernel<<<dim3(32, 8, 2), 256, 0, stream>>>(qb, kbuf, vtb, lam, nw, ab);
  out_gemm<<<dim3(64, 8), 256, 0, stream>>>(ab, wqb + 3 * 1048576, bo, (float*)d_out);
}

// Round 9
// 222.100 us; speedup vs baseline: 1.0289x; 1.0289x over previous
//
#include <hip/hip_runtime.h>
#include <hip/hip_bf16.h>

#define B_   2
#define N_   2048
#define DIM_ 1024
#define HD_  64
#define DV_  128

typedef __bf16 bf16;
typedef __bf16 bf16x8 __attribute__((ext_vector_type(8)));
typedef __bf16 bf16x4 __attribute__((ext_vector_type(4)));
typedef float  floatx4 __attribute__((ext_vector_type(4)));
typedef float  floatx16 __attribute__((ext_vector_type(16)));
typedef unsigned int uint;
typedef uint uint2v __attribute__((ext_vector_type(2)));
typedef uint uint4v __attribute__((ext_vector_type(4)));

#if __has_builtin(__builtin_amdgcn_exp2f)
#define EXP2(x) __builtin_amdgcn_exp2f(x)
#else
#define EXP2(x) exp2f(x)
#endif

// Q scale: hd^-0.5 (=1/8) with log2(e) folded in so softmax uses raw v_exp_f32 (2^x).
#define QSCALE 0.1803368801111244f

__device__ __forceinline__ void async16(const void* g, void* l) {
  __builtin_amdgcn_global_load_lds(
      (__attribute__((address_space(1))) void*)g,
      (__attribute__((address_space(3))) void*)l, 16, 0, 0);
}

__device__ __forceinline__ uint packbf(float a, float b) {
  unsigned short ul = __builtin_bit_cast(unsigned short, (bf16)a);
  unsigned short uh = __builtin_bit_cast(unsigned short, (bf16)b);
  return (uint)ul | ((uint)uh << 16);
}

// ---------------- convert fp32 -> bf16 (x + 4 weights, contiguous dst) ----------------
__global__ void convert_kernel(const float* __restrict__ x,
                               const float* __restrict__ wq,
                               const float* __restrict__ wk,
                               const float* __restrict__ wv,
                               const float* __restrict__ wo,
                               bf16* __restrict__ dst) {
  const int NX = B_ * N_ * DIM_;   // 4194304
  const int NW = DIM_ * DIM_;      // 1048576 = 2^20
  int i = (blockIdx.x * 256 + threadIdx.x) * 4;
  const float* src;
  int off;
  if (i < NX) { src = x; off = i; }
  else {
    int j = i - NX;
    int w = j >> 20;
    off = j & (NW - 1);
    src = (w == 0) ? wq : (w == 1) ? wk : (w == 2) ? wv : wo;
  }
  float4 v = *(const float4*)(src + off);
  bf16x4 o = { (bf16)v.x, (bf16)v.y, (bf16)v.z, (bf16)v.w };
  *(bf16x4*)(dst + i) = o;
}

// ---------------- lambda scalar ----------------
__global__ void lam_kernel(const float* __restrict__ lq1, const float* __restrict__ lk1,
                           const float* __restrict__ lq2, const float* __restrict__ lk2,
                           float* __restrict__ lam_out) {
  int l = threadIdx.x;  // 64 threads
  float a = lq1[l] * lk1[l];
  float b = lq2[l] * lk2[l];
  for (int m = 1; m < 64; m <<= 1) {
    a += __shfl_xor(a, m, 64);
    b += __shfl_xor(b, m, 64);
  }
  if (l == 0) *lam_out = __expf(a) - __expf(b) + 0.8f;
}

// ---------------- QKV projection GEMM (z=0:Q, 1:K, 2:V-transposed) ----------------
// R6 version (256 threads, 128x128 tiles): best measured config.
__global__ __launch_bounds__(256) void proj_kernel(
    const bf16* __restrict__ xb, const bf16* __restrict__ wall,
    const float* __restrict__ bq, const float* __restrict__ bk,
    const float* __restrict__ bv,
    bf16* __restrict__ qo, bf16* __restrict__ ko, bf16* __restrict__ vt) {
  __shared__ __align__(16) bf16 SM[2 * 128 * 64];  // At | Bt; reused as V^T tile
  bf16* At = SM;
  bf16* Bt = SM + 128 * 64;
  const int tid = threadIdx.x, lane = tid & 63, w = tid >> 6;
  const int tm = blockIdx.x, tn = blockIdx.y, z = blockIdx.z;
  const int quad = lane >> 4, l15 = lane & 15;
  const int wm = (w >> 1) * 64, wn = (w & 1) * 64;
  const bf16* Ab = xb + (long)tm * 128 * DIM_;
  const bf16* Bb = wall + (long)z * (DIM_ * DIM_) + (long)tn * 128 * DIM_;
  floatx4 zero = {0.f, 0.f, 0.f, 0.f};
  floatx4 acc[4][4];
#pragma unroll
  for (int i = 0; i < 4; ++i)
#pragma unroll
    for (int j = 0; j < 4; ++j) acc[i][j] = zero;

  for (int kb = 0; kb < DIM_ / 64; ++kb) {
    for (int idx = tid; idx < 1024; idx += 256) {
      int row = idx >> 3, ch = idx & 7, g = ch ^ (row & 7);
      async16(Ab + row * DIM_ + kb * 64 + g * 8, (char*)At + (idx - lane) * 16);
      async16(Bb + row * DIM_ + kb * 64 + g * 8, (char*)Bt + (idx - lane) * 16);
    }
    __syncthreads();
#pragma unroll
    for (int ks = 0; ks < 2; ++ks) {
      bf16x8 af[4], bfm[4];
#pragma unroll
      for (int mt = 0; mt < 4; ++mt) {
        int r = wm + mt * 16 + l15;
        af[mt] = *(const bf16x8*)&At[r * 64 + ((ks * 4 + quad) ^ (r & 7)) * 8];
      }
#pragma unroll
      for (int nt = 0; nt < 4; ++nt) {
        int r = wn + nt * 16 + l15;
        bfm[nt] = *(const bf16x8*)&Bt[r * 64 + ((ks * 4 + quad) ^ (r & 7)) * 8];
      }
#pragma unroll
      for (int mt = 0; mt < 4; ++mt)
#pragma unroll
        for (int nt = 0; nt < 4; ++nt)
          acc[mt][nt] = __builtin_amdgcn_mfma_f32_16x16x32_bf16(
              af[mt], bfm[nt], acc[mt][nt], 0, 0, 0);
    }
    __syncthreads();
  }

  if (z != 2) {
#pragma unroll
    for (int mt = 0; mt < 4; ++mt)
#pragma unroll
      for (int nt = 0; nt < 4; ++nt)
#pragma unroll
        for (int r = 0; r < 4; ++r) {
          int grow = tm * 128 + wm + mt * 16 + quad * 4 + r;
          int gcol = tn * 128 + wn + nt * 16 + l15;
          float v = acc[mt][nt][r];
          if (z == 0) {
            qo[(long)grow * DIM_ + gcol] = (bf16)((v + bq[gcol]) * QSCALE);
          } else {
            ko[(long)grow * DIM_ + gcol] = (bf16)(v + bk[gcol]);
          }
        }
  } else {
    // V epilogue: transpose through LDS, coalesced V^T row stores.
    bf16* Vl = SM;
#pragma unroll
    for (int nt = 0; nt < 4; ++nt) {
      int d = wn + nt * 16 + l15;
      float bvv = bv[tn * 128 + d];
      int m = (d & 7) * 2;
#pragma unroll
      for (int mt = 0; mt < 4; ++mt) {
        bf16x4 v4 = { (bf16)(acc[mt][nt][0] + bvv), (bf16)(acc[mt][nt][1] + bvv),
                      (bf16)(acc[mt][nt][2] + bvv), (bf16)(acc[mt][nt][3] + bvv) };
        int c = (wm >> 2) + mt * 4 + quad;
        *(bf16x4*)&Vl[d * 128 + (c ^ m) * 4] = v4;
      }
    }
    __syncthreads();
    const int bb = tm >> 4, e = tn;
    const long rowbase = ((long)(bb * 8 + e) * 128) * (long)N_ + (tm & 15) * 128;
#pragma unroll
    for (int p = 0; p < 8; ++p) {
      int d = p * 16 + (tid >> 4), j = tid & 15;
      int cs = (2 * j) ^ ((d & 7) * 2);
      bf16x8 val = *(const bf16x8*)&Vl[d * 128 + cs * 4];
      *(bf16x8*)&vt[rowbase + (long)d * N_ + j * 8] = val;
    }
  }
}

// ---------------- fused pair flash attention + diff + RMSNorm (32x32 MFMA) ------------
// One block = one (b, e, 128-query tile), 256 threads = 4 waves:
//   wave w: head hl=w&1, q-half qh=w>>1 (64 q-rows, one head).
// 32x32x16 MFMA. S^T tiles: D[m=key][n=q]: q = lane&31, key = (reg&3)+8*(reg>>2)+4h.
// P stays IN REGISTERS: exp2 -> pack bf16 pairs -> v_permlane32_swap builds the PV
// A-fragment (A[m=q=lane&31][k=key=8h+j]) with zero LDS traffic (shfl fallback).
// K/V double-buffered in LDS (64 KB total), one barrier per k-tile, prefetch
// overlaps compute. After the k-loop both K/V buffers are dead; the fp32 O1
// exchange buffer OVERLAYS them, fenced by barriers on both sides (no
// global_load_lds in flight at that point). Total LDS = 64 KB.
__global__ __launch_bounds__(256, 1) void attn_kernel(
    const bf16* __restrict__ qb, const bf16* __restrict__ kbuf,
    const bf16* __restrict__ vt, const float* __restrict__ lamp,
    const float* __restrict__ norm_w, bf16* __restrict__ ao) {
  __shared__ __align__(16) char smem[65536];
  // K buf: smem + buf*16384          [2 heads][64 keys][64 hd] bf16, 16 KB/buf
  // V buf: smem + 32768 + buf*16384  [128 d][64 keys] bf16, 16 KB/buf
  // Ob   : overlays everything after the k-loop: [128 q][128 d] fp32, 64 KB

  const int tid = threadIdx.x, lane = tid & 63, w = tid >> 6;
  const int qt = blockIdx.x, e = blockIdx.y, b = blockIdx.z;
  const int hl = w & 1, qh = w >> 1;
  const int h = lane >> 5, l31 = lane & 31;
  const int qbase = qt * 128 + qh * 64;

  // Q fragments (B-operand: B[n=q=l31][k=c*16+8h+j]), loop-invariant, from global.
  bf16x8 qf[2][4];
#pragma unroll
  for (int qs = 0; qs < 2; ++qs) {
    const bf16* qrp = qb + (long)(b * N_ + qbase + qs * 32 + l31) * DIM_
                      + e * 128 + hl * 64 + h * 8;
#pragma unroll
    for (int c = 0; c < 4; ++c) qf[qs][c] = *(const bf16x8*)(qrp + c * 16);
  }

  const bf16* kbase = kbuf + (long)b * N_ * DIM_ + e * 128;
  const bf16* vbase = vt + (long)(b * 8 + e) * DV_ * N_;

  floatx16 acc[2][4];
#pragma unroll
  for (int qs = 0; qs < 2; ++qs)
#pragma unroll
    for (int dt = 0; dt < 4; ++dt) acc[qs][dt] = floatx16{};
  float lp[2] = {0.f, 0.f};  // per-lane row-sum partial, q = l31

#define STAGE(ktv, bufv)                                                            \
  {                                                                                 \
    int kt_ = (ktv);                                                                \
    char* kdst = smem + (bufv) * 16384;                                             \
    char* vdst = smem + 32768 + (bufv) * 16384;                                     \
    _Pragma("unroll") for (int t = 0; t < 4; ++t) {                                 \
      int idx = tid + t * 256;                                                      \
      int khl = idx >> 9, row = (idx >> 3) & 63, ch = idx & 7, g = ch ^ (row & 7);  \
      async16(kbase + ((long)(kt_ * 64 + row)) * DIM_ + khl * 64 + g * 8,           \
              kdst + (idx - lane) * 16);                                            \
    }                                                                               \
    _Pragma("unroll") for (int t = 0; t < 4; ++t) {                                 \
      int idx = tid + t * 256;                                                      \
      int row = idx >> 3, ch = idx & 7, g = ch ^ (row & 7);                         \
      async16(vbase + (long)row * N_ + kt_ * 64 + g * 8,                            \
              vdst + (idx - lane) * 16);                                            \
    }                                                                               \
  }

  STAGE(0, 0);

  for (int kt = 0; kt < N_ / 64; ++kt) {
    const int buf = kt & 1;
    __syncthreads();                 // drains prefetch of buf (issued last iter)
    if (kt + 1 < N_ / 64) STAGE(kt + 1, buf ^ 1);

    const bf16* Kh = (const bf16*)(smem + buf * 16384) + hl * 4096;
    const bf16* Vb = (const bf16*)(smem + 32768 + buf * 16384);

    // hoisted fragments: K (2 keytiles x 4 hd-chunks), V (4 dtiles x 4 keychunks)
    bf16x8 kfrag[2][4], vfrag[4][4];
#pragma unroll
    for (int kt2 = 0; kt2 < 2; ++kt2)
#pragma unroll
      for (int c = 0; c < 4; ++c) {
        int row = kt2 * 32 + l31;
        kfrag[kt2][c] = *(const bf16x8*)&Kh[row * 64 + ((c * 2 + h) ^ (row & 7)) * 8];
      }
#pragma unroll
    for (int dt = 0; dt < 4; ++dt)
#pragma unroll
      for (int kc = 0; kc < 4; ++kc) {
        int row = dt * 32 + l31;
        vfrag[dt][kc] = *(const bf16x8*)&Vb[row * 64 + ((kc * 2 + h) ^ (row & 7)) * 8];
      }

#pragma unroll
    for (int qs = 0; qs < 2; ++qs) {
      bf16x8 af[2][2];
#pragma unroll
      for (int kt2 = 0; kt2 < 2; ++kt2) {
        floatx16 sv{};
#pragma unroll
        for (int c = 0; c < 4; ++c)
          sv = __builtin_amdgcn_mfma_f32_32x32x16_bf16(kfrag[kt2][c], qf[qs][c], sv, 0, 0, 0);
        // exp2 + row-sum
        float t[16];
        float s = 0.f;
#pragma unroll
        for (int i = 0; i < 16; ++i) { t[i] = EXP2(sv[i]); s += t[i]; }
        lp[qs] += s;
        // pack: d_i = 2 consecutive keys (reg pairs); key(reg) = (reg&3)+8*(reg>>2)+4h
        uint d0 = packbf(t[0], t[1]),   d1 = packbf(t[2], t[3]);
        uint d2 = packbf(t[4], t[5]),   d3 = packbf(t[6], t[7]);
        uint d4 = packbf(t[8], t[9]),   d5 = packbf(t[10], t[11]);
        uint d6 = packbf(t[12], t[13]), d7 = packbf(t[14], t[15]);
        uint4v f0, f1;
#if __has_builtin(__builtin_amdgcn_permlane32_swap)
        uint2v r02 = __builtin_amdgcn_permlane32_swap(d0, d2, false, false);
        uint2v r13 = __builtin_amdgcn_permlane32_swap(d1, d3, false, false);
        f0 = uint4v{r02.x, r13.x, r02.y, r13.y};
        uint2v r46 = __builtin_amdgcn_permlane32_swap(d4, d6, false, false);
        uint2v r57 = __builtin_amdgcn_permlane32_swap(d5, d7, false, false);
        f1 = uint4v{r46.x, r57.x, r46.y, r57.y};
#else
        uint e0 = __shfl_xor((int)d0, 32, 64), e1 = __shfl_xor((int)d1, 32, 64);
        uint e2 = __shfl_xor((int)d2, 32, 64), e3 = __shfl_xor((int)d3, 32, 64);
        uint e4 = __shfl_xor((int)d4, 32, 64), e5 = __shfl_xor((int)d5, 32, 64);
        uint e6 = __shfl_xor((int)d6, 32, 64), e7 = __shfl_xor((int)d7, 32, 64);
        f0 = h ? uint4v{e2, e3, d2, d3} : uint4v{d0, d1, e0, e1};
        f1 = h ? uint4v{e6, e7, d6, d7} : uint4v{d4, d5, e4, e5};
#endif
        af[kt2][0] = __builtin_bit_cast(bf16x8, f0);
        af[kt2][1] = __builtin_bit_cast(bf16x8, f1);
      }
      // O += P @ V : A = P[q=l31][k=key], B = V^T[d=l31][k=key]
#pragma unroll
      for (int dt = 0; dt < 4; ++dt)
#pragma unroll
        for (int kt2 = 0; kt2 < 2; ++kt2)
#pragma unroll
          for (int u = 0; u < 2; ++u)
            acc[qs][dt] = __builtin_amdgcn_mfma_f32_32x32x16_bf16(
                af[kt2][u], vfrag[dt][kt2 * 2 + u], acc[qs][dt], 0, 0, 0);
    }
  }

  // full row-sums (both lane halves hold all keys' partials for q=l31)
  lp[0] += __shfl_xor(lp[0], 32, 64);
  lp[1] += __shfl_xor(lp[1], 32, 64);

  // K/V buffers are dead from here; overlay the fp32 O1 exchange buffer.
  float* Ob = (float*)smem;  // [128 q][128 d]
  __syncthreads();           // everyone done reading K/V before h1 overwrites

  if (hl == 1) {
#pragma unroll
    for (int qs = 0; qs < 2; ++qs)
#pragma unroll
      for (int r = 0; r < 16; ++r) {
        int qloc = (r & 3) + 8 * (r >> 2) + 4 * h;
        float inv = 1.0f / __shfl(lp[qs], qloc, 64);
        float* row = &Ob[(qh * 64 + qs * 32 + qloc) * 128 + l31];
#pragma unroll
        for (int dt = 0; dt < 4; ++dt) row[dt * 32] = acc[qs][dt][r] * inv;
      }
  }
  __syncthreads();
  if (hl == 0) {
    float lam = *lamp;
    float nw4[4];
#pragma unroll
    for (int dt = 0; dt < 4; ++dt) nw4[dt] = norm_w[dt * 32 + l31] * 0.2f;
#pragma unroll
    for (int qs = 0; qs < 2; ++qs)
#pragma unroll
      for (int r = 0; r < 16; ++r) {
        int qloc = (r & 3) + 8 * (r >> 2) + 4 * h;
        float inv = 1.0f / __shfl(lp[qs], qloc, 64);
        const float* row = &Ob[(qh * 64 + qs * 32 + qloc) * 128 + l31];
        float v[4], ss = 0.f;
#pragma unroll
        for (int dt = 0; dt < 4; ++dt) {
          v[dt] = acc[qs][dt][r] * inv - lam * row[dt * 32];
          ss += v[dt] * v[dt];
        }
#pragma unroll
        for (int msk = 1; msk < 32; msk <<= 1) ss += __shfl_xor(ss, msk, 64);
        float rms = rsqrtf(ss * (1.0f / 128.0f) + 1e-5f);
        int n = qbase + qs * 32 + qloc;
        bf16* dst = ao + (long)(b * N_ + n) * DIM_ + e * DV_ + l31;
#pragma unroll
        for (int dt = 0; dt < 4; ++dt) dst[dt * 32] = (bf16)(v[dt] * rms * nw4[dt]);
      }
  }
}

// ---------------- output projection GEMM -> fp32 (R6 version) ----------------
__global__ __launch_bounds__(256) void out_gemm(
    const bf16* __restrict__ ab, const bf16* __restrict__ wo,
    const float* __restrict__ bo, float* __restrict__ out) {
  __shared__ __align__(16) bf16 At[128 * 64];
  __shared__ __align__(16) bf16 Bt[128 * 64];
  const int tid = threadIdx.x, lane = tid & 63, w = tid >> 6;
  const int tm = blockIdx.x, tn = blockIdx.y;
  const int quad = lane >> 4, l15 = lane & 15;
  const int wm = (w >> 1) * 64, wn = (w & 1) * 64;
  const bf16* Ab = ab + (long)tm * 128 * DIM_;
  const bf16* Bb = wo + (long)tn * 128 * DIM_;
  floatx4 zero = {0.f, 0.f, 0.f, 0.f};
  floatx4 acc[4][4];
#pragma unroll
  for (int i = 0; i < 4; ++i)
#pragma unroll
    for (int j = 0; j < 4; ++j) acc[i][j] = zero;

  for (int kb = 0; kb < DIM_ / 64; ++kb) {
    for (int idx = tid; idx < 1024; idx += 256) {
      int row = idx >> 3, ch = idx & 7, g = ch ^ (row & 7);
      async16(Ab + row * DIM_ + kb * 64 + g * 8, (char*)At + (idx - lane) * 16);
      async16(Bb + row * DIM_ + kb * 64 + g * 8, (char*)Bt + (idx - lane) * 16);
    }
    __syncthreads();
#pragma unroll
    for (int ks = 0; ks < 2; ++ks) {
      bf16x8 af[4], bfm[4];
#pragma unroll
      for (int mt = 0; mt < 4; ++mt) {
        int r = wm + mt * 16 + l15;
        af[mt] = *(const bf16x8*)&At[r * 64 + ((ks * 4 + quad) ^ (r & 7)) * 8];
      }
#pragma unroll
      for (int nt = 0; nt < 4; ++nt) {
        int r = wn + nt * 16 + l15;
        bfm[nt] = *(const bf16x8*)&Bt[r * 64 + ((ks * 4 + quad) ^ (r & 7)) * 8];
      }
#pragma unroll
      for (int mt = 0; mt < 4; ++mt)
#pragma unroll
        for (int nt = 0; nt < 4; ++nt)
          acc[mt][nt] = __builtin_amdgcn_mfma_f32_16x16x32_bf16(
              af[mt], bfm[nt], acc[mt][nt], 0, 0, 0);
    }
    __syncthreads();
  }
#pragma unroll
  for (int mt = 0; mt < 4; ++mt)
#pragma unroll
    for (int nt = 0; nt < 4; ++nt)
#pragma unroll
      for (int r = 0; r < 4; ++r) {
        int grow = tm * 128 + wm + mt * 16 + quad * 4 + r;
        int gcol = tn * 128 + wn + nt * 16 + l15;
        out[(long)grow * DIM_ + gcol] = acc[mt][nt][r] + bo[gcol];
      }
}

extern "C" void kernel_launch(void* const* d_in, const int* in_sizes, int n_in,
                              void* d_out, int out_size, void* d_ws, size_t ws_size,
                              hipStream_t stream) {
  const float* x    = (const float*)d_in[0];
  const float* Wq   = (const float*)d_in[1];
  const float* bq   = (const float*)d_in[2];
  const float* Wk   = (const float*)d_in[3];
  const float* bk   = (const float*)d_in[4];
  const float* Wv   = (const float*)d_in[5];
  const float* bv   = (const float*)d_in[6];
  const float* Wo   = (const float*)d_in[7];
  const float* bo   = (const float*)d_in[8];
  const float* nw   = (const float*)d_in[9];
  const float* lq1  = (const float*)d_in[10];
  const float* lk1  = (const float*)d_in[11];
  const float* lq2  = (const float*)d_in[12];
  const float* lk2  = (const float*)d_in[13];

  char* ws = (char*)d_ws;
  float* lam = (float*)ws;                     // 256 B
  bf16* xb   = (bf16*)(ws + 256);              // [4096,1024] bf16
  bf16* wqb  = xb + 4194304;                   // Wq,Wk,Wv,Wo bf16 contiguous
  bf16* qb   = wqb + 4 * 1048576;              // Q scaled  [4096,1024]
  bf16* kbuf = qb + 4194304;                   // K         [4096,1024]
  bf16* vtb  = kbuf + 4194304;                 // V^T [b,e,d,key] = [16,128,2048]
  bf16* ab   = vtb + 4194304;                  // attn out  [4096,1024]

  convert_kernel<<<8192, 256, 0, stream>>>(x, Wq, Wk, Wv, Wo, xb);
  lam_kernel<<<1, 64, 0, stream>>>(lq1, lk1, lq2, lk2, lam);
  proj_kernel<<<dim3(32, 8, 3), 256, 0, stream>>>(xb, wqb, bq, bk, bv, qb, kbuf, vtb);
  attn_kernel<<<dim3(16, 8, 2), 256, 0, stream>>>(qb, kbuf, vtb, lam, nw, ab);
  out_gemm<<<dim3(32, 8), 256, 0, stream>>>(ab, wqb + 3 * 1048576, bo, (float*)d_out);
}

// Round 11
// 221.804 us; speedup vs baseline: 1.0303x; 1.0013x over previous
//
#include <hip/hip_runtime.h>
#include <hip/hip_bf16.h>

#define B_   2
#define N_   2048
#define DIM_ 1024
#define HD_  64
#define DV_  128

typedef __bf16 bf16;
typedef __bf16 bf16x8 __attribute__((ext_vector_type(8)));
typedef __bf16 bf16x4 __attribute__((ext_vector_type(4)));
typedef float  floatx4 __attribute__((ext_vector_type(4)));
typedef float  floatx16 __attribute__((ext_vector_type(16)));
typedef unsigned int uint;
typedef uint uint2v __attribute__((ext_vector_type(2)));
typedef uint uint4v __attribute__((ext_vector_type(4)));

#if __has_builtin(__builtin_amdgcn_exp2f)
#define EXP2(x) __builtin_amdgcn_exp2f(x)
#else
#define EXP2(x) exp2f(x)
#endif

// Q scale: hd^-0.5 (=1/8) with log2(e) folded in so softmax uses raw v_exp_f32 (2^x).
#define QSCALE 0.1803368801111244f

__device__ __forceinline__ void async16(const void* g, void* l) {
  __builtin_amdgcn_global_load_lds(
      (__attribute__((address_space(1))) void*)g,
      (__attribute__((address_space(3))) void*)l, 16, 0, 0);
}

__device__ __forceinline__ uint packbf(float a, float b) {
  unsigned short ul = __builtin_bit_cast(unsigned short, (bf16)a);
  unsigned short uh = __builtin_bit_cast(unsigned short, (bf16)b);
  return (uint)ul | ((uint)uh << 16);
}

// ---------------- convert fp32 -> bf16 (x + 4 weights, contiguous dst) ----------------
__global__ void convert_kernel(const float* __restrict__ x,
                               const float* __restrict__ wq,
                               const float* __restrict__ wk,
                               const float* __restrict__ wv,
                               const float* __restrict__ wo,
                               bf16* __restrict__ dst) {
  const int NX = B_ * N_ * DIM_;   // 4194304
  const int NW = DIM_ * DIM_;      // 1048576 = 2^20
  int i = (blockIdx.x * 256 + threadIdx.x) * 4;
  const float* src;
  int off;
  if (i < NX) { src = x; off = i; }
  else {
    int j = i - NX;
    int w = j >> 20;
    off = j & (NW - 1);
    src = (w == 0) ? wq : (w == 1) ? wk : (w == 2) ? wv : wo;
  }
  float4 v = *(const float4*)(src + off);
  bf16x4 o = { (bf16)v.x, (bf16)v.y, (bf16)v.z, (bf16)v.w };
  *(bf16x4*)(dst + i) = o;
}

// ---------------- lambda scalar ----------------
__global__ void lam_kernel(const float* __restrict__ lq1, const float* __restrict__ lk1,
                           const float* __restrict__ lq2, const float* __restrict__ lk2,
                           float* __restrict__ lam_out) {
  int l = threadIdx.x;  // 64 threads
  float a = lq1[l] * lk1[l];
  float b = lq2[l] * lk2[l];
  for (int m = 1; m < 64; m <<= 1) {
    a += __shfl_xor(a, m, 64);
    b += __shfl_xor(b, m, 64);
  }
  if (l == 0) *lam_out = __expf(a) - __expf(b) + 0.8f;
}

// ---------------- QKV projection GEMM (z=0:Q, 1:K, 2:V-transposed) ----------------
// R6 version (256 threads, 128x128 tiles): best measured config.
__global__ __launch_bounds__(256) void proj_kernel(
    const bf16* __restrict__ xb, const bf16* __restrict__ wall,
    const float* __restrict__ bq, const float* __restrict__ bk,
    const float* __restrict__ bv,
    bf16* __restrict__ qo, bf16* __restrict__ ko, bf16* __restrict__ vt) {
  __shared__ __align__(16) bf16 SM[2 * 128 * 64];  // At | Bt; reused as V^T tile
  bf16* At = SM;
  bf16* Bt = SM + 128 * 64;
  const int tid = threadIdx.x, lane = tid & 63, w = tid >> 6;
  const int tm = blockIdx.x, tn = blockIdx.y, z = blockIdx.z;
  const int quad = lane >> 4, l15 = lane & 15;
  const int wm = (w >> 1) * 64, wn = (w & 1) * 64;
  const bf16* Ab = xb + (long)tm * 128 * DIM_;
  const bf16* Bb = wall + (long)z * (DIM_ * DIM_) + (long)tn * 128 * DIM_;
  floatx4 zero = {0.f, 0.f, 0.f, 0.f};
  floatx4 acc[4][4];
#pragma unroll
  for (int i = 0; i < 4; ++i)
#pragma unroll
    for (int j = 0; j < 4; ++j) acc[i][j] = zero;

  for (int kb = 0; kb < DIM_ / 64; ++kb) {
    for (int idx = tid; idx < 1024; idx += 256) {
      int row = idx >> 3, ch = idx & 7, g = ch ^ (row & 7);
      async16(Ab + row * DIM_ + kb * 64 + g * 8, (char*)At + (idx - lane) * 16);
      async16(Bb + row * DIM_ + kb * 64 + g * 8, (char*)Bt + (idx - lane) * 16);
    }
    __syncthreads();
#pragma unroll
    for (int ks = 0; ks < 2; ++ks) {
      bf16x8 af[4], bfm[4];
#pragma unroll
      for (int mt = 0; mt < 4; ++mt) {
        int r = wm + mt * 16 + l15;
        af[mt] = *(const bf16x8*)&At[r * 64 + ((ks * 4 + quad) ^ (r & 7)) * 8];
      }
#pragma unroll
      for (int nt = 0; nt < 4; ++nt) {
        int r = wn + nt * 16 + l15;
        bfm[nt] = *(const bf16x8*)&Bt[r * 64 + ((ks * 4 + quad) ^ (r & 7)) * 8];
      }
#pragma unroll
      for (int mt = 0; mt < 4; ++mt)
#pragma unroll
        for (int nt = 0; nt < 4; ++nt)
          acc[mt][nt] = __builtin_amdgcn_mfma_f32_16x16x32_bf16(
              af[mt], bfm[nt], acc[mt][nt], 0, 0, 0);
    }
    __syncthreads();
  }

  if (z != 2) {
#pragma unroll
    for (int mt = 0; mt < 4; ++mt)
#pragma unroll
      for (int nt = 0; nt < 4; ++nt)
#pragma unroll
        for (int r = 0; r < 4; ++r) {
          int grow = tm * 128 + wm + mt * 16 + quad * 4 + r;
          int gcol = tn * 128 + wn + nt * 16 + l15;
          float v = acc[mt][nt][r];
          if (z == 0) {
            qo[(long)grow * DIM_ + gcol] = (bf16)((v + bq[gcol]) * QSCALE);
          } else {
            ko[(long)grow * DIM_ + gcol] = (bf16)(v + bk[gcol]);
          }
        }
  } else {
    // V epilogue: transpose through LDS, coalesced V^T row stores.
    bf16* Vl = SM;
#pragma unroll
    for (int nt = 0; nt < 4; ++nt) {
      int d = wn + nt * 16 + l15;
      float bvv = bv[tn * 128 + d];
      int m = (d & 7) * 2;
#pragma unroll
      for (int mt = 0; mt < 4; ++mt) {
        bf16x4 v4 = { (bf16)(acc[mt][nt][0] + bvv), (bf16)(acc[mt][nt][1] + bvv),
                      (bf16)(acc[mt][nt][2] + bvv), (bf16)(acc[mt][nt][3] + bvv) };
        int c = (wm >> 2) + mt * 4 + quad;
        *(bf16x4*)&Vl[d * 128 + (c ^ m) * 4] = v4;
      }
    }
    __syncthreads();
    const int bb = tm >> 4, e = tn;
    const long rowbase = ((long)(bb * 8 + e) * 128) * (long)N_ + (tm & 15) * 128;
#pragma unroll
    for (int p = 0; p < 8; ++p) {
      int d = p * 16 + (tid >> 4), j = tid & 15;
      int cs = (2 * j) ^ ((d & 7) * 2);
      bf16x8 val = *(const bf16x8*)&Vl[d * 128 + cs * 4];
      *(bf16x8*)&vt[rowbase + (long)d * N_ + j * 8] = val;
    }
  }
}

// ---------------- fused pair flash attention + diff + RMSNorm (32x32 MFMA) ------------
// R9 structure; bank-conflict fix: staging swizzle folds (row>>3)&3 into the
// chunk XOR so fragment-read bank groups vary across all 32 consecutive rows a
// half-wave touches (R9's (row&7)-only swizzle gave lanes {p,p+8,p+16,p+24}
// identical banks -> 3.1M SQ_LDS_BANK_CONFLICT). Readers adjusted to match.
__global__ __launch_bounds__(256, 1) void attn_kernel(
    const bf16* __restrict__ qb, const bf16* __restrict__ kbuf,
    const bf16* __restrict__ vt, const float* __restrict__ lamp,
    const float* __restrict__ norm_w, bf16* __restrict__ ao) {
  __shared__ __align__(16) char smem[65536];
  // K buf: smem + buf*16384          [2 heads][64 keys][64 hd] bf16, 16 KB/buf
  // V buf: smem + 32768 + buf*16384  [128 d][64 keys] bf16, 16 KB/buf
  // Ob   : overlays everything after the k-loop: [128 q][128 d] fp32, 64 KB

  const int tid = threadIdx.x, lane = tid & 63, w = tid >> 6;
  const int qt = blockIdx.x, e = blockIdx.y, b = blockIdx.z;
  const int hl = w & 1, qh = w >> 1;
  const int h = lane >> 5, l31 = lane & 31;
  const int qbase = qt * 128 + qh * 64;

  // Q fragments (B-operand: B[n=q=l31][k=c*16+8h+j]), loop-invariant, from global.
  bf16x8 qf[2][4];
#pragma unroll
  for (int qs = 0; qs < 2; ++qs) {
    const bf16* qrp = qb + (long)(b * N_ + qbase + qs * 32 + l31) * DIM_
                      + e * 128 + hl * 64 + h * 8;
#pragma unroll
    for (int c = 0; c < 4; ++c) qf[qs][c] = *(const bf16x8*)(qrp + c * 16);
  }

  const bf16* kbase = kbuf + (long)b * N_ * DIM_ + e * 128;
  const bf16* vbase = vt + (long)(b * 8 + e) * DV_ * N_;

  floatx16 acc[2][4];
#pragma unroll
  for (int qs = 0; qs < 2; ++qs)
#pragma unroll
    for (int dt = 0; dt < 4; ++dt) acc[qs][dt] = floatx16{};
  float lp[2] = {0.f, 0.f};  // per-lane row-sum partial, q = l31

#define STAGE(ktv, bufv)                                                            \
  {                                                                                 \
    int kt_ = (ktv);                                                                \
    char* kdst = smem + (bufv) * 16384;                                             \
    char* vdst = smem + 32768 + (bufv) * 16384;                                     \
    _Pragma("unroll") for (int t = 0; t < 4; ++t) {                                 \
      int idx = tid + t * 256;                                                      \
      int khl = idx >> 9, row = (idx >> 3) & 63, ch = idx & 7;                      \
      int g = ch ^ (row & 7) ^ ((row >> 3) & 3);                                    \
      async16(kbase + ((long)(kt_ * 64 + row)) * DIM_ + khl * 64 + g * 8,           \
              kdst + (idx - lane) * 16);                                            \
    }                                                                               \
    _Pragma("unroll") for (int t = 0; t < 4; ++t) {                                 \
      int idx = tid + t * 256;                                                      \
      int row = idx >> 3, ch = idx & 7;                                             \
      int g = ch ^ (row & 7) ^ ((row >> 3) & 3);                                    \
      async16(vbase + (long)row * N_ + kt_ * 64 + g * 8,                            \
              vdst + (idx - lane) * 16);                                            \
    }                                                                               \
  }

  STAGE(0, 0);

  for (int kt = 0; kt < N_ / 64; ++kt) {
    const int buf = kt & 1;
    __syncthreads();                 // drains prefetch of buf (issued last iter)
    if (kt + 1 < N_ / 64) STAGE(kt + 1, buf ^ 1);

    const bf16* Kh = (const bf16*)(smem + buf * 16384) + hl * 4096;
    const bf16* Vb = (const bf16*)(smem + 32768 + buf * 16384);

    // hoisted fragments: K (2 keytiles x 4 hd-chunks), V (4 dtiles x 4 keychunks)
    bf16x8 kfrag[2][4], vfrag[4][4];
#pragma unroll
    for (int kt2 = 0; kt2 < 2; ++kt2)
#pragma unroll
      for (int c = 0; c < 4; ++c) {
        int row = kt2 * 32 + l31;
        int sw = (c * 2 + h) ^ (row & 7) ^ ((row >> 3) & 3);
        kfrag[kt2][c] = *(const bf16x8*)&Kh[row * 64 + sw * 8];
      }
#pragma unroll
    for (int dt = 0; dt < 4; ++dt)
#pragma unroll
      for (int kc = 0; kc < 4; ++kc) {
        int row = dt * 32 + l31;
        int sw = (kc * 2 + h) ^ (row & 7) ^ ((row >> 3) & 3);
        vfrag[dt][kc] = *(const bf16x8*)&Vb[row * 64 + sw * 8];
      }

#pragma unroll
    for (int qs = 0; qs < 2; ++qs) {
      bf16x8 af[2][2];
#pragma unroll
      for (int kt2 = 0; kt2 < 2; ++kt2) {
        floatx16 sv{};
#pragma unroll
        for (int c = 0; c < 4; ++c)
          sv = __builtin_amdgcn_mfma_f32_32x32x16_bf16(kfrag[kt2][c], qf[qs][c], sv, 0, 0, 0);
        // exp2 + row-sum
        float t[16];
        float s = 0.f;
#pragma unroll
        for (int i = 0; i < 16; ++i) { t[i] = EXP2(sv[i]); s += t[i]; }
        lp[qs] += s;
        // pack: d_i = 2 consecutive keys (reg pairs); key(reg) = (reg&3)+8*(reg>>2)+4h
        uint d0 = packbf(t[0], t[1]),   d1 = packbf(t[2], t[3]);
        uint d2 = packbf(t[4], t[5]),   d3 = packbf(t[6], t[7]);
        uint d4 = packbf(t[8], t[9]),   d5 = packbf(t[10], t[11]);
        uint d6 = packbf(t[12], t[13]), d7 = packbf(t[14], t[15]);
        uint4v f0, f1;
#if __has_builtin(__builtin_amdgcn_permlane32_swap)
        uint2v r02 = __builtin_amdgcn_permlane32_swap(d0, d2, false, false);
        uint2v r13 = __builtin_amdgcn_permlane32_swap(d1, d3, false, false);
        f0 = uint4v{r02.x, r13.x, r02.y, r13.y};
        uint2v r46 = __builtin_amdgcn_permlane32_swap(d4, d6, false, false);
        uint2v r57 = __builtin_amdgcn_permlane32_swap(d5, d7, false, false);
        f1 = uint4v{r46.x, r57.x, r46.y, r57.y};
#else
        uint e0 = __shfl_xor((int)d0, 32, 64), e1 = __shfl_xor((int)d1, 32, 64);
        uint e2 = __shfl_xor((int)d2, 32, 64), e3 = __shfl_xor((int)d3, 32, 64);
        uint e4 = __shfl_xor((int)d4, 32, 64), e5 = __shfl_xor((int)d5, 32, 64);
        uint e6 = __shfl_xor((int)d6, 32, 64), e7 = __shfl_xor((int)d7, 32, 64);
        f0 = h ? uint4v{e2, e3, d2, d3} : uint4v{d0, d1, e0, e1};
        f1 = h ? uint4v{e6, e7, d6, d7} : uint4v{d4, d5, e4, e5};
#endif
        af[kt2][0] = __builtin_bit_cast(bf16x8, f0);
        af[kt2][1] = __builtin_bit_cast(bf16x8, f1);
      }
      // O += P @ V : A = P[q=l31][k=key], B = V^T[d=l31][k=key]
#pragma unroll
      for (int dt = 0; dt < 4; ++dt)
#pragma unroll
        for (int kt2 = 0; kt2 < 2; ++kt2)
#pragma unroll
          for (int u = 0; u < 2; ++u)
            acc[qs][dt] = __builtin_amdgcn_mfma_f32_32x32x16_bf16(
                af[kt2][u], vfrag[dt][kt2 * 2 + u], acc[qs][dt], 0, 0, 0);
    }
  }

  // full row-sums (both lane halves hold all keys' partials for q=l31)
  lp[0] += __shfl_xor(lp[0], 32, 64);
  lp[1] += __shfl_xor(lp[1], 32, 64);

  // K/V buffers are dead from here; overlay the fp32 O1 exchange buffer.
  float* Ob = (float*)smem;  // [128 q][128 d]
  __syncthreads();           // everyone done reading K/V before h1 overwrites

  if (hl == 1) {
#pragma unroll
    for (int qs = 0; qs < 2; ++qs)
#pragma unroll
      for (int r = 0; r < 16; ++r) {
        int qloc = (r & 3) + 8 * (r >> 2) + 4 * h;
        float inv = 1.0f / __shfl(lp[qs], qloc, 64);
        float* row = &Ob[(qh * 64 + qs * 32 + qloc) * 128 + l31];
#pragma unroll
        for (int dt = 0; dt < 4; ++dt) row[dt * 32] = acc[qs][dt][r] * inv;
      }
  }
  __syncthreads();
  if (hl == 0) {
    float lam = *lamp;
    float nw4[4];
#pragma unroll
    for (int dt = 0; dt < 4; ++dt) nw4[dt] = norm_w[dt * 32 + l31] * 0.2f;
#pragma unroll
    for (int qs = 0; qs < 2; ++qs)
#pragma unroll
      for (int r = 0; r < 16; ++r) {
        int qloc = (r & 3) + 8 * (r >> 2) + 4 * h;
        float inv = 1.0f / __shfl(lp[qs], qloc, 64);
        const float* row = &Ob[(qh * 64 + qs * 32 + qloc) * 128 + l31];
        float v[4], ss = 0.f;
#pragma unroll
        for (int dt = 0; dt < 4; ++dt) {
          v[dt] = acc[qs][dt][r] * inv - lam * row[dt * 32];
          ss += v[dt] * v[dt];
        }
#pragma unroll
        for (int msk = 1; msk < 32; msk <<= 1) ss += __shfl_xor(ss, msk, 64);
        float rms = rsqrtf(ss * (1.0f / 128.0f) + 1e-5f);
        int n = qbase + qs * 32 + qloc;
        bf16* dst = ao + (long)(b * N_ + n) * DIM_ + e * DV_ + l31;
#pragma unroll
        for (int dt = 0; dt < 4; ++dt) dst[dt * 32] = (bf16)(v[dt] * rms * nw4[dt]);
      }
  }
}

// ---------------- output projection GEMM -> fp32 ----------------
// 128x128 tile kept (A/B reuse), but 512 threads = 8 waves (wave 32x64):
// 2 waves/SIMD at grid 256 vs R6's 1 wave/SIMD — isolated occupancy fix.
__global__ __launch_bounds__(512) void out_gemm(
    const bf16* __restrict__ ab, const bf16* __restrict__ wo,
    const float* __restrict__ bo, float* __restrict__ out) {
  __shared__ __align__(16) bf16 At[128 * 64];
  __shared__ __align__(16) bf16 Bt[128 * 64];
  const int tid = threadIdx.x, lane = tid & 63, w = tid >> 6;
  const int tm = blockIdx.x, tn = blockIdx.y;
  const int quad = lane >> 4, l15 = lane & 15;
  const int wm = (w & 3) * 32, wn = (w >> 2) * 64;
  const bf16* Ab = ab + (long)tm * 128 * DIM_;
  const bf16* Bb = wo + (long)tn * 128 * DIM_;
  floatx4 zero = {0.f, 0.f, 0.f, 0.f};
  floatx4 acc[2][4];
#pragma unroll
  for (int i = 0; i < 2; ++i)
#pragma unroll
    for (int j = 0; j < 4; ++j) acc[i][j] = zero;

  for (int kb = 0; kb < DIM_ / 64; ++kb) {
    for (int idx = tid; idx < 1024; idx += 512) {
      int row = idx >> 3, ch = idx & 7, g = ch ^ (row & 7);
      async16(Ab + row * DIM_ + kb * 64 + g * 8, (char*)At + (idx - lane) * 16);
      async16(Bb + row * DIM_ + kb * 64 + g * 8, (char*)Bt + (idx - lane) * 16);
    }
    __syncthreads();
#pragma unroll
    for (int ks = 0; ks < 2; ++ks) {
      bf16x8 af[2], bfm[4];
#pragma unroll
      for (int mt = 0; mt < 2; ++mt) {
        int r = wm + mt * 16 + l15;
        af[mt] = *(const bf16x8*)&At[r * 64 + ((ks * 4 + quad) ^ (r & 7)) * 8];
      }
#pragma unroll
      for (int nt = 0; nt < 4; ++nt) {
        int r = wn + nt * 16 + l15;
        bfm[nt] = *(const bf16x8*)&Bt[r * 64 + ((ks * 4 + quad) ^ (r & 7)) * 8];
      }
#pragma unroll
      for (int mt = 0; mt < 2; ++mt)
#pragma unroll
        for (int nt = 0; nt < 4; ++nt)
          acc[mt][nt] = __builtin_amdgcn_mfma_f32_16x16x32_bf16(
              af[mt], bfm[nt], acc[mt][nt], 0, 0, 0);
    }
    __syncthreads();
  }
#pragma unroll
  for (int mt = 0; mt < 2; ++mt)
#pragma unroll
    for (int nt = 0; nt < 4; ++nt)
#pragma unroll
      for (int r = 0; r < 4; ++r) {
        int grow = tm * 128 + wm + mt * 16 + quad * 4 + r;
        int gcol = tn * 128 + wn + nt * 16 + l15;
        out[(long)grow * DIM_ + gcol] = acc[mt][nt][r] + bo[gcol];
      }
}

extern "C" void kernel_launch(void* const* d_in, const int* in_sizes, int n_in,
                              void* d_out, int out_size, void* d_ws, size_t ws_size,
                              hipStream_t stream) {
  const float* x    = (const float*)d_in[0];
  const float* Wq   = (const float*)d_in[1];
  const float* bq   = (const float*)d_in[2];
  const float* Wk   = (const float*)d_in[3];
  const float* bk   = (const float*)d_in[4];
  const float* Wv   = (const float*)d_in[5];
  const float* bv   = (const float*)d_in[6];
  const float* Wo   = (const float*)d_in[7];
  const float* bo   = (const float*)d_in[8];
  const float* nw   = (const float*)d_in[9];
  const float* lq1  = (const float*)d_in[10];
  const float* lk1  = (const float*)d_in[11];
  const float* lq2  = (const float*)d_in[12];
  const float* lk2  = (const float*)d_in[13];

  char* ws = (char*)d_ws;
  float* lam = (float*)ws;                     // 256 B
  bf16* xb   = (bf16*)(ws + 256);              // [4096,1024] bf16
  bf16* wqb  = xb + 4194304;                   // Wq,Wk,Wv,Wo bf16 contiguous
  bf16* qb   = wqb + 4 * 1048576;              // Q scaled  [4096,1024]
  bf16* kbuf = qb + 4194304;                   // K         [4096,1024]
  bf16* vtb  = kbuf + 4194304;                 // V^T [b,e,d,key] = [16,128,2048]
  bf16* ab   = vtb + 4194304;                  // attn out  [4096,1024]

  convert_kernel<<<8192, 256, 0, stream>>>(x, Wq, Wk, Wv, Wo, xb);
  lam_kernel<<<1, 64, 0, stream>>>(lq1, lk1, lq2, lk2, lam);
  proj_kernel<<<dim3(32, 8, 3), 256, 0, stream>>>(xb, wqb, bq, bk, bv, qb, kbuf, vtb);
  attn_kernel<<<dim3(16, 8, 2), 256, 0, stream>>>(qb, kbuf, vtb, lam, nw, ab);
  out_gemm<<<dim3(32, 8), 512, 0, stream>>>(ab, wqb + 3 * 1048576, bo, (float*)d_out);
}